// Round 6
// baseline (593.097 us; speedup 1.0000x reference)
//
#include <hip/hip_runtime.h>

// Correlation volume, N=8, Z=128, H=W=160, 81 shifts (9 dy x 9 dx).
// v6 = r5 with the barrier cadence halved: chunk ZC 2->4 z-slices
// (32 chunks, 32 barriers), NBUF 4->3 (distance 2), exactly 2
// global_load_lds per thread per prefetch. Lane mapping, grid (800 blocks
// of 9 waves, bid%8 = image -> XCD), and compute layout identical to r5.
#define NB 8
#define ZD 128
#define HD 160
#define WD 160
#define PLANE (HD * WD)            // 25600
#define IMG (ZD * PLANE)

#define TI 8
#define TJ 32
#define COLT 5                     // col tiles; 20 row tiles -> 100 tiles/img
#define NTHREADS 576               // 9 waves; wave w = dy index
#define ZC 4
#define NCHUNK (ZD / ZC)           // 32

#define ASL 9                      // A 16B-slots/row (8 data + 1 pad)
#define BSL 11                     // B 16B-slots/row (10 data + 1 pad)
#define BROWS 16                   // B row window (8 + 8 halo)
#define A_SLOTS (ZC * TI * ASL)    // 288
#define B_SLOTS (ZC * BROWS * BSL) // 704
#define REAL_SLOTS (A_SLOTS + B_SLOTS) // 992
#define BUF_SLOTS 1024             // padded; slots >= 992 are dead pad
#define NBUF 3                     // prefetch distance 2

#define GP(x) ((const __attribute__((address_space(1))) void*)(x))
#define LP(x) ((__attribute__((address_space(3))) void*)(x))

__global__ __launch_bounds__(NTHREADS, 6)
void corr_vol_kernel(const float* __restrict__ A, const float* __restrict__ B,
                     const float* __restrict__ zp, float* __restrict__ out) {
    __shared__ float4 lds[NBUF * BUF_SLOTS];   // 48 KB
    __shared__ float4 dump[64];                // sink for dummy loads

    const int tid = threadIdx.x;
    const int bid = blockIdx.x;
    const int n  = bid & 7;            // XCD = image
    const int s  = bid >> 3;           // tile 0..99
    const int it = s / COLT, jt = s - COLT * it;
    const int i0 = it * TI, j0 = jt * TJ;

    const float* Abase = A + (size_t)n * IMG;
    const float* Bbase = B + (size_t)n * IMG;

    // ---- staging descriptor for LDS slot s: A [0,288), B [288,992), pad ----
    auto decode = [&](int slot, const float*& p, int& st) {
        if (slot < A_SLOTS) {
            const int zA = slot / (TI * ASL), rem = slot % (TI * ASL);
            const int rA = rem / ASL, cA = rem % ASL;
            const bool v = (cA < 8);
            p = v ? Abase + (size_t)zA * PLANE + (size_t)(i0 + rA) * WD + (j0 + 4 * cA) : zp;
            st = v ? ZC * PLANE : 0;
        } else if (slot < REAL_SLOTS) {
            const int q = slot - A_SLOTS;
            const int zB = q / (BROWS * BSL), rem = q % (BROWS * BSL);
            const int rB = rem / BSL, cB = rem % BSL;
            const int gr = i0 - 4 + rB, gc = j0 - 4 + 4 * cB;
            const bool v = (cB < 10) && ((unsigned)gr < (unsigned)HD) &&
                           ((unsigned)gc < (unsigned)WD);
            p = v ? Bbase + (size_t)zB * PLANE + (size_t)gr * WD + gc : zp;
            st = v ? ZC * PLANE : 0;
        } else {                       // pad slot or beyond-buffer dummy
            p = zp; st = 0;
        }
    };

    const float *p1, *p2; int st1, st2;
    decode(tid, p1, st1);                       // slot1 = tid  (< 1024 always)
    decode(tid + NTHREADS, p2, st2);            // slot2 = tid + 576
    const bool in2 = (tid + NTHREADS < BUF_SLOTS);   // tid < 448: wave-uniform
    const unsigned d1 = (unsigned)(tid & ~63);
    const unsigned d2 = (unsigned)((tid + NTHREADS) & ~63);
    const float* pp1 = p1;
    const float* pp2 = p2;

    // Exactly 2 global_load_lds per thread per prefetch -> exact vmcnt math.
    auto prefetch = [&](int k2, int pb) {
        char* base = (char*)&lds[pb * BUF_SLOTS];
        if (k2 < NCHUNK) {
            __builtin_amdgcn_global_load_lds(GP(pp1), LP(base + 16u * d1), 16, 0, 0);
            __builtin_amdgcn_global_load_lds(GP(pp2),
                LP(in2 ? base + 16u * d2 : (char*)&dump[0]), 16, 0, 0);
            pp1 += st1; pp2 += st2;
        } else {  // tail dummies keep per-wave outstanding-count uniform
            __builtin_amdgcn_global_load_lds(GP(zp), LP((char*)&dump[0]), 16, 0, 0);
            __builtin_amdgcn_global_load_lds(GP(zp), LP((char*)&dump[0]), 16, 0, 0);
        }
    };

    const int w = tid >> 6;            // dy index 0..8
    const int l = tid & 63;
    const int r = l >> 3;              // pixel row 0..7
    const int g = l & 7;               // col group (4 cols each)

    // LDS float offsets (constant per thread)
    const int aoff = ASL * 4 * r + 4 * g;              // within A z-slice
    const int boff = BSL * 4 * (r + w) + 4 * g;        // within B z-slice

    float acc[9][4];
    #pragma unroll
    for (int d = 0; d < 9; ++d)
        #pragma unroll
        for (int q = 0; q < 4; ++q) acc[d][q] = 0.f;

    prefetch(0, 0);
    prefetch(1, 1);

#define STEP(k, rb, pb) do {                                                    \
    asm volatile("s_waitcnt vmcnt(2)\n\ts_barrier" ::: "memory");               \
    prefetch((k) + 2, (pb));                                                    \
    const float* Af = (const float*)&lds[(rb) * BUF_SLOTS];                     \
    _Pragma("unroll")                                                           \
    for (int z = 0; z < ZC; ++z) {                                              \
        const float* az = Af + z * (TI * ASL * 4) + aoff;                       \
        const float* bz = Af + 4 * A_SLOTS + z * (BROWS * BSL * 4) + boff;      \
        float a[4], b[12];                                                      \
        *(float4*)&a[0] = *(const float4*)(az);                                 \
        *(float4*)&b[0] = *(const float4*)(bz);                                 \
        *(float4*)&b[4] = *(const float4*)(bz + 4);                             \
        *(float4*)&b[8] = *(const float4*)(bz + 8);                             \
        _Pragma("unroll")                                                       \
        for (int d = 0; d < 9; ++d)                                             \
            _Pragma("unroll")                                                   \
            for (int q = 0; q < 4; ++q)                                         \
                acc[d][q] = fmaf(a[q], b[q + d], acc[d][q]);                    \
    }                                                                           \
} while (0)

    // 32 chunks, buffers rotate mod 3.
    for (int m = 0; m < 10; ++m) {
        const int k = 3 * m;
        STEP(k + 0, 0, 2);
        STEP(k + 1, 1, 0);
        STEP(k + 2, 2, 1);
    }
    STEP(30, 0, 2);
    STEP(31, 1, 0);
#undef STEP

    asm volatile("s_waitcnt vmcnt(0)" ::: "memory");  // drain tail dummies

    // ---- epilogue: out[k = d*9 + w] (d = x-shift, w = y-shift) ----
    #pragma unroll
    for (int d = 0; d < 9; ++d) {
        const int kk = d * 9 + w;
        float* o = out + (((size_t)(n * 81 + kk)) * HD + (i0 + r)) * WD + j0 + 4 * g;
        *(float4*)o = make_float4(acc[d][0], acc[d][1], acc[d][2], acc[d][3]);
    }
}

extern "C" void kernel_launch(void* const* d_in, const int* in_sizes, int n_in,
                              void* d_out, int out_size, void* d_ws, size_t ws_size,
                              hipStream_t stream) {
    const float* A = (const float*)d_in[0];
    const float* B = (const float*)d_in[1];
    float* out = (float*)d_out;
    // 256 B zero page for OOB/pad staging lanes (d_ws re-poisoned every launch).
    hipMemsetAsync(d_ws, 0, 256, stream);
    corr_vol_kernel<<<dim3(NB * 100), dim3(NTHREADS), 0, stream>>>(
        A, B, (const float*)d_ws, out);
}

// Round 7
// 294.901 us; speedup vs baseline: 2.0112x; 2.0112x over previous
//
#include <hip/hip_runtime.h>

// Correlation volume, N=8, Z=128, H=W=160, 81 shifts (9 dy x 9 dx).
// v7 = r5 (best structure: ZC=2, NBUF=4/distance-3, 1 global_load_lds per
// thread per prefetch, 800 blocks of 9 waves, bid%8 = image -> XCD) with ONE
// change: __launch_bounds__ (576,6) -> (576,4). r5/r6 counters showed the
// (576,6) register cap forced scratch spills (WRITE_SIZE 119/410 MB vs the
// 66 MB output); r0 under (576,4) had WRITE == output exactly (no spill).
#define NB 8
#define ZD 128
#define HD 160
#define WD 160
#define PLANE (HD * WD)            // 25600
#define IMG (ZD * PLANE)

#define TI 8
#define TJ 32
#define COLT 5                     // col tiles; 20 row tiles -> 100 tiles/img
#define NTHREADS 576               // 9 waves; wave w = dy index
#define ZC 2
#define NCHUNK (ZD / ZC)           // 64

#define ASL 9                      // A 16B-slots/row (8 data + 1 pad)
#define BSL 11                     // B 16B-slots/row (10 data + 1 pad)
#define BROWS 16                   // B row window (8 + 8 halo)
#define A_SLOTS (ZC * TI * ASL)    // 144
#define B_SLOTS (ZC * BROWS * BSL) // 352
#define REAL_SLOTS (A_SLOTS + B_SLOTS) // 496
#define BUF_SLOTS 512              // padded; slots >= 496 are dead pad
#define NBUF 4                     // prefetch distance 3

#define GP(x) ((const __attribute__((address_space(1))) void*)(x))
#define LP(x) ((__attribute__((address_space(3))) void*)(x))

__global__ __launch_bounds__(NTHREADS, 4)
void corr_vol_kernel(const float* __restrict__ A, const float* __restrict__ B,
                     const float* __restrict__ zp, float* __restrict__ out) {
    __shared__ float4 lds[NBUF * BUF_SLOTS];   // 32 KB
    __shared__ float4 dump[64];                // sink for wave-8 / tail dummies

    const int tid = threadIdx.x;
    const int bid = blockIdx.x;
    const int n  = bid & 7;            // XCD = image
    const int s  = bid >> 3;           // tile 0..99
    const int it = s / COLT, jt = s - COLT * it;
    const int i0 = it * TI, j0 = jt * TJ;

    const float* Abase = A + (size_t)n * IMG;
    const float* Bbase = B + (size_t)n * IMG;

    // ---- staging descriptor: slot = tid (A [0,144), B [144,496), pad/dummy) ----
    const float* p; int st;
    if (tid < A_SLOTS) {
        const int zA = tid / (TI * ASL), rem = tid % (TI * ASL);
        const int rA = rem / ASL, cA = rem % ASL;
        const bool v = (cA < 8);
        p = v ? Abase + (size_t)zA * PLANE + (size_t)(i0 + rA) * WD + (j0 + 4 * cA) : zp;
        st = v ? ZC * PLANE : 0;
    } else if (tid < REAL_SLOTS) {
        const int q = tid - A_SLOTS;
        const int zB = q / (BROWS * BSL), rem = q % (BROWS * BSL);
        const int rB = rem / BSL, cB = rem % BSL;
        const int gr = i0 - 4 + rB, gc = j0 - 4 + 4 * cB;
        const bool v = (cB < 10) && ((unsigned)gr < (unsigned)HD) &&
                       ((unsigned)gc < (unsigned)WD);
        p = v ? Bbase + (size_t)zB * PLANE + (size_t)gr * WD + gc : zp;
        st = v ? ZC * PLANE : 0;
    } else {                           // pad slots 496..511 and wave 8
        p = zp; st = 0;
    }
    const bool in_buf = (tid < BUF_SLOTS);            // wave-uniform (512 = 8*64)
    const unsigned dslot = (unsigned)(tid & ~63);     // wave-uniform slot base
    const float* pp = p;

    // Exactly 1 global_load_lds per thread per prefetch -> exact vmcnt math.
    auto prefetch = [&](int k2, int pb) {
        char* base = (char*)&lds[pb * BUF_SLOTS];
        if (k2 < NCHUNK) {
            __builtin_amdgcn_global_load_lds(GP(pp),
                LP(in_buf ? base + 16u * dslot : (char*)&dump[0]), 16, 0, 0);
            pp += st;
        } else {  // tail dummy keeps per-wave outstanding-count uniform
            __builtin_amdgcn_global_load_lds(GP(zp), LP((char*)&dump[0]), 16, 0, 0);
        }
    };

    const int w = tid >> 6;            // dy index 0..8
    const int l = tid & 63;
    const int r = l >> 3;              // pixel row 0..7
    const int g = l & 7;               // col group (4 cols each)

    // LDS float offsets (constant per thread)
    const int aoff = ASL * 4 * r + 4 * g;              // within A z-slice
    const int boff = BSL * 4 * (r + w) + 4 * g;        // within B z-slice

    float acc[9][4];
    #pragma unroll
    for (int d = 0; d < 9; ++d)
        #pragma unroll
        for (int q = 0; q < 4; ++q) acc[d][q] = 0.f;

    prefetch(0, 0);
    prefetch(1, 1);
    prefetch(2, 2);

#define STEP(k, rb, pb) do {                                                    \
    asm volatile("s_waitcnt vmcnt(2)\n\ts_barrier" ::: "memory");               \
    prefetch((k) + 3, (pb));                                                    \
    const float* Af = (const float*)&lds[(rb) * BUF_SLOTS];                     \
    _Pragma("unroll")                                                           \
    for (int z = 0; z < ZC; ++z) {                                              \
        const float* az = Af + z * (TI * ASL * 4) + aoff;                       \
        const float* bz = Af + 4 * A_SLOTS + z * (BROWS * BSL * 4) + boff;      \
        float a[4], b[12];                                                      \
        *(float4*)&a[0] = *(const float4*)(az);                                 \
        *(float4*)&b[0] = *(const float4*)(bz);                                 \
        *(float4*)&b[4] = *(const float4*)(bz + 4);                             \
        *(float4*)&b[8] = *(const float4*)(bz + 8);                             \
        _Pragma("unroll")                                                       \
        for (int d = 0; d < 9; ++d)                                             \
            _Pragma("unroll")                                                   \
            for (int q = 0; q < 4; ++q)                                         \
                acc[d][q] = fmaf(a[q], b[q + d], acc[d][q]);                    \
    }                                                                           \
} while (0)

    for (int m = 0; m < NCHUNK / 4; ++m) {
        const int k = 4 * m;
        STEP(k + 0, 0, 3);
        STEP(k + 1, 1, 0);
        STEP(k + 2, 2, 1);
        STEP(k + 3, 3, 2);
    }
#undef STEP

    asm volatile("s_waitcnt vmcnt(0)" ::: "memory");  // drain tail dummies

    // ---- epilogue: out[k = d*9 + w] (d = x-shift, w = y-shift) ----
    #pragma unroll
    for (int d = 0; d < 9; ++d) {
        const int kk = d * 9 + w;
        float* o = out + (((size_t)(n * 81 + kk)) * HD + (i0 + r)) * WD + j0 + 4 * g;
        *(float4*)o = make_float4(acc[d][0], acc[d][1], acc[d][2], acc[d][3]);
    }
}

extern "C" void kernel_launch(void* const* d_in, const int* in_sizes, int n_in,
                              void* d_out, int out_size, void* d_ws, size_t ws_size,
                              hipStream_t stream) {
    const float* A = (const float*)d_in[0];
    const float* B = (const float*)d_in[1];
    float* out = (float*)d_out;
    // 256 B zero page for OOB/pad staging lanes (d_ws re-poisoned every launch).
    hipMemsetAsync(d_ws, 0, 256, stream);
    corr_vol_kernel<<<dim3(NB * 100), dim3(NTHREADS), 0, stream>>>(
        A, B, (const float*)d_ws, out);
}